// Round 1
// baseline (250.412 us; speedup 1.0000x reference)
//
#include <hip/hip_runtime.h>
#include <hip/hip_bf16.h>

typedef __attribute__((ext_vector_type(8))) short short8;
typedef __attribute__((ext_vector_type(4))) float f32x4;

namespace {
constexpr int kC = 256;      // channels
constexpr int kH = 4000;     // h dim
constexpr int kNW = 800;     // windows per batch (kH / kP)
constexpr int kP = 5;
constexpr int kHeads = 8;
constexpr int kDH = 32;
constexpr float kScale = 0.17677669529663687f; // 32^-0.5

constexpr int WPB = 8;            // windows per block
constexpr int ROWS = WPB * kP;    // 40 rows of xw per block
constexpr int MT = 3;             // M-tiles of 16 (48 rows, 8 padding)
constexpr int NTHR = 512;         // 8 waves
constexpr int COLP = 258;         // qkv LDS col stride (bank spread)

constexpr int WQKV_PACKED = 3 * 16 * 8 * 64 * 8; // 196608 bf16
constexpr int WOUT_PACKED = 16 * 8 * 64 * 8;     // 65536 bf16
}

// Pack W_qkv (256x768 f32) and W_out (256x256 f32) into bf16 MFMA
// B-fragment order: [..nt..][kt][lane][8] so each lane loads 16B contiguous.
// B mapping for mfma_f32_16x16x32_bf16: col = lane&15, k = (lane>>4)*8 + i.
__global__ void prep_weights(const float* __restrict__ Wqkv,
                             const float* __restrict__ Wout,
                             __hip_bfloat16* __restrict__ wq_p,
                             __hip_bfloat16* __restrict__ wo_p) {
  int idx = blockIdx.x * 256 + threadIdx.x;
  if (idx < WQKV_PACKED) {
    int i = idx & 7;
    int l = (idx >> 3) & 63;
    int kt = (idx >> 9) & 7;
    int nt = (idx >> 12) & 15;
    int part = idx >> 16;
    int k = kt * 32 + (l >> 4) * 8 + i;
    int col = part * 256 + nt * 16 + (l & 15);
    wq_p[idx] = __float2bfloat16(Wqkv[k * 768 + col]);
  }
  if (idx < WOUT_PACKED) {
    int i = idx & 7;
    int l = (idx >> 3) & 63;
    int kt = (idx >> 9) & 7;
    int nt = (idx >> 12) & 15;
    int k = kt * 32 + (l >> 4) * 8 + i;
    int col = nt * 16 + (l & 15);
    wo_p[idx] = __float2bfloat16(Wout[k * 256 + col]);
  }
}

__global__ __launch_bounds__(NTHR) void local_attn_kernel(
    const float* __restrict__ x, const short* __restrict__ wq_p,
    const short* __restrict__ wo_p, const float* __restrict__ b_out,
    float* __restrict__ g_out, float* __restrict__ g_attn) {
  // smA: bf16 [48][256], XOR-swizzled rows; holds Xt then (reused) attn-out.
  __shared__ __align__(16) char smAbuf[48 * 512];
  __shared__ __align__(16) __hip_bfloat16 smQKV[3][ROWS][COLP];
  __shared__ __align__(16) float attnP[WPB][kHeads][kP][kP];

  const int tid = threadIdx.x;
  const int lane = tid & 63;
  const int wid = tid >> 6;

  const int widx0 = blockIdx.x * WPB;      // global window index base
  const int bi = widx0 / kNW;
  const int w0 = widx0 % kNW;
  const int h0 = w0 * kP;

  // ---- Phase 1: stage Xt = x[bi][:, h0:h0+40] transposed to [row=h][col=c]
  {
    const float* xb = x + (size_t)bi * kC * kH + h0;
    for (int i = tid; i < kC * ROWS; i += NTHR) {
      int c = i / ROWS, hh = i % ROWS;
      float v = xb[c * kH + hh];
      int cb = c * 2;
      *(__hip_bfloat16*)(smAbuf + hh * 512 + (cb ^ ((hh & 7) << 4))) =
          __float2bfloat16(v);
    }
  }
  __syncthreads();

  // ---- Phase 2: GEMM1  qkv = Xt(48x256) @ Wqkv(256x768), per part q/k/v
  // wave handles ntiles {2*wid, 2*wid+1} (cols wid*32 .. wid*32+31) per part
  for (int part = 0; part < 3; ++part) {
    f32x4 acc[MT][2];
#pragma unroll
    for (int m = 0; m < MT; ++m)
#pragma unroll
      for (int n = 0; n < 2; ++n) acc[m][n] = (f32x4){0.f, 0.f, 0.f, 0.f};

#pragma unroll
    for (int kt = 0; kt < 8; ++kt) {
      short8 a[MT];
#pragma unroll
      for (int m = 0; m < MT; ++m) {
        int row = m * 16 + (lane & 15);
        int kb = kt * 64 + ((lane >> 4) << 4);
        a[m] = *(const short8*)(smAbuf + row * 512 + (kb ^ ((row & 7) << 4)));
      }
      short8 b[2];
#pragma unroll
      for (int n = 0; n < 2; ++n) {
        int nt = wid * 2 + n;
        b[n] = *(const short8*)(wq_p +
                                ((((part * 16 + nt) * 8 + kt) * 64 + lane) * 8));
      }
#pragma unroll
      for (int m = 0; m < MT; ++m)
#pragma unroll
        for (int n = 0; n < 2; ++n)
          acc[m][n] =
              __builtin_amdgcn_mfma_f32_16x16x32_bf16(a[m], b[n], acc[m][n], 0, 0, 0);
    }
    // write qkv part to LDS (C/D layout: col=lane&15, row=(lane>>4)*4+r)
#pragma unroll
    for (int m = 0; m < MT; ++m)
#pragma unroll
      for (int n = 0; n < 2; ++n)
#pragma unroll
        for (int r = 0; r < 4; ++r) {
          int row = m * 16 + ((lane >> 4) << 2) + r;
          if (row < ROWS) {
            int col = (wid * 2 + n) * 16 + (lane & 15);
            smQKV[part][row][col] = __float2bfloat16(acc[m][n][r]);
          }
        }
  }
  __syncthreads();

  // ---- Phase 3: dots + softmax (fp32 scalar; mask is row-constant -> no-op)
  for (int task = tid; task < WPB * kHeads * kP; task += NTHR) {
    int wl = task / (kHeads * kP);
    int rem = task % (kHeads * kP);
    int head = rem / kP, i = rem % kP;
    int qrow = wl * kP + i;
    float qv[kDH];
    const __hip_bfloat16* qp = &smQKV[0][qrow][head * kDH];
#pragma unroll
    for (int d = 0; d < kDH; ++d) qv[d] = __bfloat162float(qp[d]);
    float dots[kP];
    float mx = -1e30f;
#pragma unroll
    for (int j = 0; j < kP; ++j) {
      const __hip_bfloat16* kp = &smQKV[1][wl * kP + j][head * kDH];
      float s = 0.f;
#pragma unroll
      for (int d = 0; d < kDH; ++d) s += qv[d] * __bfloat162float(kp[d]);
      s *= kScale;
      dots[j] = s;
      mx = fmaxf(mx, s);
    }
    float sum = 0.f;
#pragma unroll
    for (int j = 0; j < kP; ++j) {
      dots[j] = __expf(dots[j] - mx);
      sum += dots[j];
    }
    float inv = 1.f / sum;
#pragma unroll
    for (int j = 0; j < kP; ++j) attnP[wl][head][i][j] = dots[j] * inv;
  }
  __syncthreads();

  // ---- Phase 4a: write attn to global (layout matches exactly; contiguous)
  {
    const float* ap = (const float*)attnP;
    for (int i = tid; i < WPB * kHeads * kP * kP; i += NTHR)
      g_attn[(size_t)widx0 * (kHeads * kP * kP) + i] = ap[i];
  }
  // ---- Phase 4b: PV -> attn-out into smA (swizzled bf16), rows 40-47 stale/ignored
  for (int task = tid; task < WPB * kHeads * kP * kDH; task += NTHR) {
    int wl = task / (kHeads * kP * kDH);
    int rem = task % (kHeads * kP * kDH);
    int head = rem / (kP * kDH);
    int rem2 = rem % (kP * kDH);
    int i = rem2 / kDH, d = rem2 % kDH;
    float s = 0.f;
#pragma unroll
    for (int j = 0; j < kP; ++j)
      s += attnP[wl][head][i][j] *
           __bfloat162float(smQKV[2][wl * kP + j][head * kDH + d]);
    int row = wl * kP + i, col = head * kDH + d;
    *(__hip_bfloat16*)(smAbuf + row * 512 + ((col * 2) ^ ((row & 7) << 4))) =
        __float2bfloat16(s);
  }
  __syncthreads();

  // ---- Phase 5: GEMM2  out2 = attnout(48x256) @ Wout(256x256) + b_out
  f32x4 acc2[MT][2];
#pragma unroll
  for (int m = 0; m < MT; ++m)
#pragma unroll
    for (int n = 0; n < 2; ++n) acc2[m][n] = (f32x4){0.f, 0.f, 0.f, 0.f};

#pragma unroll
  for (int kt = 0; kt < 8; ++kt) {
    short8 a[MT];
#pragma unroll
    for (int m = 0; m < MT; ++m) {
      int row = m * 16 + (lane & 15);
      int kb = kt * 64 + ((lane >> 4) << 4);
      a[m] = *(const short8*)(smAbuf + row * 512 + (kb ^ ((row & 7) << 4)));
    }
    short8 b[2];
#pragma unroll
    for (int n = 0; n < 2; ++n) {
      int nt = wid * 2 + n;
      b[n] = *(const short8*)(wo_p + (((nt * 8 + kt) * 64 + lane) * 8));
    }
#pragma unroll
    for (int m = 0; m < MT; ++m)
#pragma unroll
      for (int n = 0; n < 2; ++n)
        acc2[m][n] =
            __builtin_amdgcn_mfma_f32_16x16x32_bf16(a[m], b[n], acc2[m][n], 0, 0, 0);
  }

  // epilogue: +bias, stage to LDS [c][hh] for coalesced writeback.
  // smQKV is dead now -> reuse as float outstage [256][41]
  float* outS = (float*)&smQKV[0][0][0];
#pragma unroll
  for (int n = 0; n < 2; ++n) {
    int col = (wid * 2 + n) * 16 + (lane & 15);
    float bias = b_out[col];
#pragma unroll
    for (int m = 0; m < MT; ++m)
#pragma unroll
      for (int r = 0; r < 4; ++r) {
        int row = m * 16 + ((lane >> 4) << 2) + r;
        if (row < ROWS) outS[col * 41 + row] = acc2[m][n][r] + bias;
      }
  }
  __syncthreads();

  // ---- Phase 6: coalesced global writeback out[bi][c][h0+hh]
  {
    float* op = g_out + (size_t)bi * kC * kH + h0;
    for (int i = tid; i < kC * ROWS; i += NTHR) {
      int c = i / ROWS, hh = i % ROWS;
      op[c * kH + hh] = outS[c * 41 + hh];
    }
  }
}

extern "C" void kernel_launch(void* const* d_in, const int* in_sizes, int n_in,
                              void* d_out, int out_size, void* d_ws,
                              size_t ws_size, hipStream_t stream) {
  const float* x = (const float*)d_in[0];
  const float* Wqkv = (const float*)d_in[1];
  const float* Wout = (const float*)d_in[2];
  const float* bout = (const float*)d_in[3];
  // d_in[4] (pos_embedding) is provably a no-op: its bias is constant along
  // the softmax axis.

  short* wq_p = (short*)d_ws;
  short* wo_p = wq_p + WQKV_PACKED;

  prep_weights<<<WQKV_PACKED / 256, 256, 0, stream>>>(
      Wqkv, Wout, (__hip_bfloat16*)wq_p, (__hip_bfloat16*)wo_p);

  float* g_out = (float*)d_out;
  float* g_attn = g_out + (size_t)32 * kC * kH;

  int nblocks = (32 * kNW) / WPB;  // 3200
  local_attn_kernel<<<nblocks, NTHR, 0, stream>>>(x, wq_p, wo_p, bout, g_out,
                                                  g_attn);
}

// Round 2
// 168.902 us; speedup vs baseline: 1.4826x; 1.4826x over previous
//
#include <hip/hip_runtime.h>
#include <hip/hip_bf16.h>

typedef __attribute__((ext_vector_type(8))) short short8;
typedef __attribute__((ext_vector_type(4))) float f32x4;

namespace {
constexpr int kC = 256;
constexpr int kH = 4000;
constexpr int kNW = 800;     // windows per batch
constexpr int kP = 5;
constexpr int kHeads = 8;
constexpr int kDH = 32;
constexpr float kScale = 0.17677669529663687f; // 32^-0.5

constexpr int WPB = 8;          // windows per block
constexpr int ROWS = WPB * kP;  // 40
constexpr int MT = 3;           // M-tiles of 16 (rows 40..47 are junk)
constexpr int NTHR = 512;       // 8 waves

constexpr int WQKV_PACKED = 3 * 16 * 8 * 64 * 8;
constexpr int WOUT_PACKED = 16 * 8 * 64 * 8;

// LDS map (single 80KB arena -> 2 blocks/CU)
// smA   : bytes [0, 20480)      40 rows x 512B bf16, xor-swizzled
//         (fragment reads touch rows 40..47 -> alias into qkv region; junk ok)
// smQKV : bytes [20480, 81920)  3 parts x 40 rows x 512B bf16, xor-swizzled
// outS  : reuses smQKV region as float [256][41] for writeback staging
constexpr int QKV_OFF = 20480;
constexpr int PART_STRIDE = 20480;
constexpr int SM_TOTAL = 81920;
}

__device__ inline float b2f(short s) {
  union { unsigned u; float f; } v;
  v.u = ((unsigned)(unsigned short)s) << 16;
  return v.f;
}
__device__ inline short f2bs(float f) {
  __hip_bfloat16 h = __float2bfloat16(f);
  return *reinterpret_cast<short*>(&h);
}

// Pack W_qkv (256x768) / W_out (256x256) f32 -> bf16 MFMA B-fragment order:
// [part][nt][kt][lane][8], B mapping: col = lane&15, k = (lane>>4)*8 + i.
__global__ void prep_weights(const float* __restrict__ Wqkv,
                             const float* __restrict__ Wout,
                             __hip_bfloat16* __restrict__ wq_p,
                             __hip_bfloat16* __restrict__ wo_p) {
  int idx = blockIdx.x * 256 + threadIdx.x;
  if (idx < WQKV_PACKED) {
    int i = idx & 7;
    int l = (idx >> 3) & 63;
    int kt = (idx >> 9) & 7;
    int nt = (idx >> 12) & 15;
    int part = idx >> 16;
    int k = kt * 32 + (l >> 4) * 8 + i;
    int col = part * 256 + nt * 16 + (l & 15);
    wq_p[idx] = __float2bfloat16(Wqkv[k * 768 + col]);
  }
  if (idx < WOUT_PACKED) {
    int i = idx & 7;
    int l = (idx >> 3) & 63;
    int kt = (idx >> 9) & 7;
    int nt = (idx >> 12) & 15;
    int k = kt * 32 + (l >> 4) * 8 + i;
    int col = nt * 16 + (l & 15);
    wo_p[idx] = __float2bfloat16(Wout[k * 256 + col]);
  }
}

__global__ __launch_bounds__(NTHR, 4) void local_attn_kernel(
    const float* __restrict__ x, const short* __restrict__ wq_p,
    const short* __restrict__ wo_p, const float* __restrict__ b_out,
    float* __restrict__ g_out, float* __restrict__ g_attn) {
  __shared__ __align__(16) char smem[SM_TOTAL];

  const int tid = threadIdx.x;
  const int lane = tid & 63;
  const int wid = tid >> 6;

  const int widx0 = blockIdx.x * WPB;
  const int bi = widx0 / kNW;
  const int h0 = (widx0 % kNW) * kP;

  // ---- Phase 1: stage Xt (transposed x slice) into smA, bf16 swizzled
  {
    const float* xb = x + (size_t)bi * kC * kH + h0;
    for (int i = tid; i < kC * ROWS; i += NTHR) {
      int c = i / ROWS, hh = i % ROWS;
      *(__hip_bfloat16*)(smem + hh * 512 + ((c * 2) ^ ((hh & 7) << 4))) =
          __float2bfloat16(xb[c * kH + hh]);
    }
  }
  __syncthreads();

  // ---- Phase 2: GEMM1 qkv = Xt(48x256) @ Wqkv(256x768)
  // wave wid computes cols wid*32..wid*32+31 of each part == head wid slice
  for (int part = 0; part < 3; ++part) {
    f32x4 acc[MT][2];
#pragma unroll
    for (int m = 0; m < MT; ++m)
#pragma unroll
      for (int n = 0; n < 2; ++n) acc[m][n] = (f32x4){0.f, 0.f, 0.f, 0.f};

#pragma unroll
    for (int kt = 0; kt < 8; ++kt) {
      short8 a[MT];
#pragma unroll
      for (int m = 0; m < MT; ++m) {
        int row = m * 16 + (lane & 15);
        int kb = kt * 64 + ((lane >> 4) << 4);
        a[m] = *(const short8*)(smem + row * 512 + (kb ^ ((row & 7) << 4)));
      }
      short8 b[2];
#pragma unroll
      for (int n = 0; n < 2; ++n) {
        int nt = wid * 2 + n;
        b[n] = *(const short8*)(wq_p +
                                ((((part * 16 + nt) * 8 + kt) * 64 + lane) * 8));
      }
#pragma unroll
      for (int m = 0; m < MT; ++m)
#pragma unroll
        for (int n = 0; n < 2; ++n)
          acc[m][n] = __builtin_amdgcn_mfma_f32_16x16x32_bf16(a[m], b[n],
                                                              acc[m][n], 0, 0, 0);
    }
    // store qkv part (C/D: col=lane&15, row=(lane>>4)*4+r)
#pragma unroll
    for (int m = 0; m < MT; ++m)
#pragma unroll
      for (int n = 0; n < 2; ++n)
#pragma unroll
        for (int r = 0; r < 4; ++r) {
          int row = m * 16 + ((lane >> 4) << 2) + r;
          if (row < ROWS) {
            int col = (wid * 2 + n) * 16 + (lane & 15);
            *(__hip_bfloat16*)(smem + QKV_OFF + part * PART_STRIDE + row * 512 +
                               ((col * 2) ^ ((row & 7) << 4))) =
                __float2bfloat16(acc[m][n][r]);
          }
        }
  }
  __syncthreads();

  // ---- Phase 3+4 fused: per-(window,head,qrow) dots+softmax+attn-write+PV
  if (tid < WPB * kHeads * kP) {
    int wl = tid / (kHeads * kP);
    int rem = tid % (kHeads * kP);
    int head = rem / kP, i = rem % kP;
    int qrow = wl * kP + i;
    int qsw = (qrow & 7) << 4;
    const char* qbase = smem + QKV_OFF + qrow * 512;

    float qf[32];
#pragma unroll
    for (int ch = 0; ch < 4; ++ch) {
      short8 v8 = *(const short8*)(qbase + ((head * 64 + ch * 16) ^ qsw));
#pragma unroll
      for (int e = 0; e < 8; ++e) qf[ch * 8 + e] = b2f(v8[e]);
    }

    float dots[kP];
    float mx = -1e30f;
#pragma unroll
    for (int j = 0; j < kP; ++j) {
      int krow = wl * kP + j;
      const char* kbase = smem + QKV_OFF + PART_STRIDE + krow * 512;
      int ksw = (krow & 7) << 4;
      float s = 0.f;
#pragma unroll
      for (int ch = 0; ch < 4; ++ch) {
        short8 kv = *(const short8*)(kbase + ((head * 64 + ch * 16) ^ ksw));
#pragma unroll
        for (int e = 0; e < 8; ++e) s += qf[ch * 8 + e] * b2f(kv[e]);
      }
      s *= kScale;
      dots[j] = s;
      mx = fmaxf(mx, s);
    }
    float sum = 0.f;
#pragma unroll
    for (int j = 0; j < kP; ++j) {
      dots[j] = __expf(dots[j] - mx);
      sum += dots[j];
    }
    float inv = 1.f / sum;

    // attn probs -> global (dense across wave: thread t writes floats 5t..5t+4)
    float* ap = g_attn + (size_t)widx0 * (kHeads * kP * kP) + tid * kP;
#pragma unroll
    for (int j = 0; j < kP; ++j) {
      dots[j] *= inv;
      ap[j] = dots[j];
    }

    // PV: out[d] = sum_j attn[j] * v[j][d]
    float ov[32];
#pragma unroll
    for (int d = 0; d < 32; ++d) ov[d] = 0.f;
#pragma unroll
    for (int j = 0; j < kP; ++j) {
      float aj = dots[j];
      int vrow = wl * kP + j;
      const char* vbase = smem + QKV_OFF + 2 * PART_STRIDE + vrow * 512;
      int vsw = (vrow & 7) << 4;
#pragma unroll
      for (int ch = 0; ch < 4; ++ch) {
        short8 vv = *(const short8*)(vbase + ((head * 64 + ch * 16) ^ vsw));
#pragma unroll
        for (int e = 0; e < 8; ++e) ov[ch * 8 + e] += aj * b2f(vv[e]);
      }
    }
    // pack bf16, vector-write into smA (same row/col swizzle as Xt)
    char* obase = smem + qrow * 512;
#pragma unroll
    for (int ch = 0; ch < 4; ++ch) {
      short8 o8;
#pragma unroll
      for (int e = 0; e < 8; ++e) o8[e] = f2bs(ov[ch * 8 + e]);
      *(short8*)(obase + ((head * 64 + ch * 16) ^ qsw)) = o8;
    }
  }
  __syncthreads();

  // ---- Phase 5: GEMM2 out2 = attnout(48x256) @ Wout(256x256) + b_out
  f32x4 acc2[MT][2];
#pragma unroll
  for (int m = 0; m < MT; ++m)
#pragma unroll
    for (int n = 0; n < 2; ++n) acc2[m][n] = (f32x4){0.f, 0.f, 0.f, 0.f};

#pragma unroll
  for (int kt = 0; kt < 8; ++kt) {
    short8 a[MT];
#pragma unroll
    for (int m = 0; m < MT; ++m) {
      int row = m * 16 + (lane & 15);
      int kb = kt * 64 + ((lane >> 4) << 4);
      a[m] = *(const short8*)(smem + row * 512 + (kb ^ ((row & 7) << 4)));
    }
    short8 b[2];
#pragma unroll
    for (int n = 0; n < 2; ++n) {
      int nt = wid * 2 + n;
      b[n] = *(const short8*)(wo_p + (((nt * 8 + kt) * 64 + lane) * 8));
    }
#pragma unroll
    for (int m = 0; m < MT; ++m)
#pragma unroll
      for (int n = 0; n < 2; ++n)
        acc2[m][n] = __builtin_amdgcn_mfma_f32_16x16x32_bf16(a[m], b[n],
                                                             acc2[m][n], 0, 0, 0);
  }

  // epilogue: +bias, stage as float [256][41] in qkv region (dead now)
  float* outS = (float*)(smem + QKV_OFF);
#pragma unroll
  for (int n = 0; n < 2; ++n) {
    int col = (wid * 2 + n) * 16 + (lane & 15);
    float bias = b_out[col];
#pragma unroll
    for (int m = 0; m < MT; ++m)
#pragma unroll
      for (int r = 0; r < 4; ++r) {
        int row = m * 16 + ((lane >> 4) << 2) + r;
        if (row < ROWS) outS[col * 41 + row] = acc2[m][n][r] + bias;
      }
  }
  __syncthreads();

  // ---- Phase 6: coalesced writeback out[bi][c][h0+hh]
  {
    float* op = g_out + (size_t)bi * kC * kH + h0;
    for (int i = tid; i < kC * ROWS; i += NTHR) {
      int c = i / ROWS, hh = i % ROWS;
      op[c * kH + hh] = outS[c * 41 + hh];
    }
  }
}

extern "C" void kernel_launch(void* const* d_in, const int* in_sizes, int n_in,
                              void* d_out, int out_size, void* d_ws,
                              size_t ws_size, hipStream_t stream) {
  const float* x = (const float*)d_in[0];
  const float* Wqkv = (const float*)d_in[1];
  const float* Wout = (const float*)d_in[2];
  const float* bout = (const float*)d_in[3];
  // d_in[4] (pos_embedding) provably cancels in softmax (row-constant bias).

  short* wq_p = (short*)d_ws;
  short* wo_p = wq_p + WQKV_PACKED;

  prep_weights<<<WQKV_PACKED / 256, 256, 0, stream>>>(
      Wqkv, Wout, (__hip_bfloat16*)wq_p, (__hip_bfloat16*)wo_p);

  float* g_out = (float*)d_out;
  float* g_attn = g_out + (size_t)32 * kC * kH;

  int nblocks = (32 * kNW) / WPB;  // 3200
  local_attn_kernel<<<nblocks, NTHR, 0, stream>>>(x, wq_p, wo_p, bout, g_out,
                                                  g_attn);
}